// Round 10
// baseline (272.108 us; speedup 1.0000x reference)
//
#include <hip/hip_runtime.h>

// MultiResolutionHashEncoding — Morton-sorted, level-phased.
// 1) 15-bit Morton counting-sort of points (hist/scan/scatter) -> xs4[] with
//    orig index in .w. Wave-adjacent points become spatially adjacent ->
//    corner-line sharing at coarse/mid levels (TA coalesce + L1 dedup).
// 2) One gather level per launch (hard inter-level barrier -> one 4 MiB
//    slice active per XCD L2). Parity trick: PRIMES[0]==1 -> even ux pairs
//    corners {2k,2k+1} -> one float4 load (avg 6 lines/pt, not 8).
// 3) ws slabs stored as bf16x2 (uint) -> all 15 slabs = 30 MiB; last kernel
//    does l15 + reads slabs + scatter-writes 128 B/point to out[orig].
// R8 lesson kept: only full-line output writes.
//
// Scalings floor(16*growth^l) with f32 semantics of the reference
// (growth rounds DOWN in f32 => level 15 scaling is 2047, not 2048).
__device__ __constant__ float c_scal[16] = {
    16.f, 22.f, 30.f, 42.f, 58.f, 80.f, 111.f, 153.f,
    212.f, 294.f, 406.f, 561.f, 776.f, 1072.f, 1482.f, 2047.f
};

#define TBL_T 524288u   // 2^19 entries per level
#define NPTS  524288u
#define TMASK (TBL_T - 1u)
#define NBUCK 32768u    // 2^15 Morton buckets (5 bits/axis)

// ---------- bf16x2 pack/unpack (RNE) ----------
__device__ __forceinline__ unsigned pack_bf2(float a, float b) {
    unsigned ua = __float_as_uint(a), ub = __float_as_uint(b);
    ua = (ua + 0x7FFFu + ((ua >> 16) & 1u)) >> 16;
    ub = (ub + 0x7FFFu + ((ub >> 16) & 1u)) >> 16;
    return ua | (ub << 16);
}
__device__ __forceinline__ float2 unpack_bf2(unsigned u) {
    return make_float2(__uint_as_float(u << 16),
                       __uint_as_float(u & 0xFFFF0000u));
}

// ---------- Morton ----------
__device__ __forceinline__ unsigned part1by2(unsigned v) {
    v &= 0x3FFu;
    v = (v | (v << 16)) & 0xFF0000FFu;
    v = (v | (v << 8))  & 0x0F00F00Fu;
    v = (v | (v << 4))  & 0xC30C30C3u;
    v = (v | (v << 2))  & 0x49249249u;
    return v;
}
__device__ __forceinline__ unsigned morton_key(float px, float py, float pz) {
    unsigned kx = min(31u, (unsigned)(px * 32.f));
    unsigned ky = min(31u, (unsigned)(py * 32.f));
    unsigned kz = min(31u, (unsigned)(pz * 32.f));
    return (part1by2(kx) << 2) | (part1by2(ky) << 1) | part1by2(kz);
}

// ---------- core: one level's feature, parity-split gather ----------
__device__ __forceinline__ float2 level_feat(
        const float2* __restrict__ tbl, float px, float py, float pz,
        float s, unsigned base) {
    float sx = px * s, sy = py * s, sz = pz * s;
    float cx = floorf(sx), cy = floorf(sy), cz = floorf(sz);
    float fx = sx - cx, fy = sy - cy, fz = sz - cz;

    unsigned ux = (unsigned)cx, uy = (unsigned)cy, uz = (unsigned)cz;

    unsigned hy0 = uy * 2654435761u, hy1 = (uy + 1u) * 2654435761u;
    unsigned hz0 = uz * 805459861u,  hz1 = (uz + 1u) * 805459861u;

    float wx1 = fx, wx0 = 1.f - fx;
    float wy1 = fy, wy0 = 1.f - fy;
    float wz1 = fz, wz0 = 1.f - fz;

    float wyz[4] = { wy0 * wz0, wy0 * wz1, wy1 * wz0, wy1 * wz1 };
    unsigned hyz[4] = { hy0 ^ hz0, hy0 ^ hz1, hy1 ^ hz0, hy1 ^ hz1 };

    float o0 = 0.f, o1 = 0.f;

    if ((ux & 1u) == 0u) {
        float4 f[4];
#pragma unroll
        for (int j = 0; j < 4; ++j) {
            unsigned idx0 = ((ux ^ hyz[j]) & TMASK) + base;
            f[j] = *reinterpret_cast<const float4*>(
                       reinterpret_cast<const float*>(tbl) + ((idx0 & ~1u) << 1));
        }
#pragma unroll
        for (int j = 0; j < 4; ++j) {
            unsigned idx0 = ((ux ^ hyz[j]) & TMASK) + base;
            bool hi0 = (idx0 & 1u) != 0u;
            float c0x = hi0 ? f[j].z : f[j].x;
            float c0y = hi0 ? f[j].w : f[j].y;
            float c1x = hi0 ? f[j].x : f[j].z;
            float c1y = hi0 ? f[j].y : f[j].w;
            o0 += c0x * (wx0 * wyz[j]) + c1x * (wx1 * wyz[j]);
            o1 += c0y * (wx0 * wyz[j]) + c1y * (wx1 * wyz[j]);
        }
    } else {
        unsigned ux1 = ux + 1u;
        float2 v0[4], v1[4];
#pragma unroll
        for (int j = 0; j < 4; ++j) {
            v0[j] = tbl[((ux  ^ hyz[j]) & TMASK) + base];
            v1[j] = tbl[((ux1 ^ hyz[j]) & TMASK) + base];
        }
#pragma unroll
        for (int j = 0; j < 4; ++j) {
            o0 += v0[j].x * (wx0 * wyz[j]) + v1[j].x * (wx1 * wyz[j]);
            o1 += v0[j].y * (wx0 * wyz[j]) + v1[j].y * (wx1 * wyz[j]);
        }
    }
    return make_float2(o0, o1);
}

// ---------- sort pipeline ----------
__global__ __launch_bounds__(1024) void zero_hist(unsigned* __restrict__ h) {
    h[blockIdx.x * 1024u + threadIdx.x] = 0u;
}

__global__ __launch_bounds__(256) void hist_k(
        const float* __restrict__ x, unsigned* __restrict__ hist) {
    unsigned p = blockIdx.x * 256u + threadIdx.x;
    unsigned key = morton_key(x[p * 3], x[p * 3 + 1], x[p * 3 + 2]);
    atomicAdd(&hist[key], 1u);
}

__global__ __launch_bounds__(1024) void scan32k(unsigned* __restrict__ hist) {
    __shared__ unsigned part[1024];
    unsigned t = threadIdx.x;
    unsigned base = t * 32u;
    unsigned vals[32]; unsigned sum = 0u;
#pragma unroll
    for (int i = 0; i < 32; ++i) { vals[i] = hist[base + i]; sum += vals[i]; }
    part[t] = sum;
    __syncthreads();
    for (unsigned off = 1; off < 1024; off <<= 1) {
        unsigned v = (t >= off) ? part[t - off] : 0u;
        __syncthreads();
        part[t] += v;
        __syncthreads();
    }
    unsigned run = part[t] - sum;   // exclusive prefix over chunks
#pragma unroll
    for (int i = 0; i < 32; ++i) { hist[base + i] = run; run += vals[i]; }
}

__global__ __launch_bounds__(256) void scatter_k(
        const float* __restrict__ x, unsigned* __restrict__ cursor,
        float4* __restrict__ xs4) {
    unsigned p = blockIdx.x * 256u + threadIdx.x;
    float px = x[p * 3], py = x[p * 3 + 1], pz = x[p * 3 + 2];
    unsigned key = morton_key(px, py, pz);
    unsigned pos = atomicAdd(&cursor[key], 1u);
    xs4[pos] = make_float4(px, py, pz, __uint_as_float(p));
}

// ---------- sorted gather kernels ----------
__global__ __launch_bounds__(256) void coarse_s(
        const float4* __restrict__ xs4, const float2* __restrict__ tbl,
        unsigned* __restrict__ slabs) {
    unsigned p = blockIdx.x * 256u + threadIdx.x;
    float4 X = xs4[p];
#pragma unroll
    for (int l = 0; l < 5; ++l) {
        float2 f = level_feat(tbl, X.x, X.y, X.z, c_scal[l], (unsigned)l * TBL_T);
        slabs[(size_t)l * NPTS + p] = pack_bf2(f.x, f.y);
    }
}

__global__ __launch_bounds__(256) void level_s(
        const float4* __restrict__ xs4, const float2* __restrict__ tbl,
        unsigned* __restrict__ slabs, int l) {
    unsigned p = blockIdx.x * 256u + threadIdx.x;
    float4 X = xs4[p];
    float2 f = level_feat(tbl, X.x, X.y, X.z, c_scal[l], (unsigned)l * TBL_T);
    slabs[(size_t)l * NPTS + p] = pack_bf2(f.x, f.y);
}

// last: level 15 gather + decode 15 slabs + scatter 128 B/point to out[orig]
__global__ __launch_bounds__(256) void last_s(
        const float4* __restrict__ xs4, const float2* __restrict__ tbl,
        const unsigned* __restrict__ slabs, float4* __restrict__ out) {
    unsigned p = blockIdx.x * 256u + threadIdx.x;
    float4 X = xs4[p];
    float2 f15 = level_feat(tbl, X.x, X.y, X.z, c_scal[15], 15u * TBL_T);

    float2 v[16];
#pragma unroll
    for (int l = 0; l < 15; ++l) v[l] = unpack_bf2(slabs[(size_t)l * NPTS + p]);
    v[15] = f15;

    unsigned orig = __float_as_uint(X.w);
    float4* dst = out + (size_t)orig * 8u;
#pragma unroll
    for (int q = 0; q < 8; ++q)
        dst[q] = make_float4(v[2 * q].x, v[2 * q].y, v[2 * q + 1].x, v[2 * q + 1].y);
}

// ---------- fallback (no ws): single kernel ----------
__global__ __launch_bounds__(256) void hashenc_mono(
        const float* __restrict__ x, const float2* __restrict__ tbl,
        float4* __restrict__ out) {
    unsigned p = blockIdx.x * 256u + threadIdx.x;
    float px = x[p * 3], py = x[p * 3 + 1], pz = x[p * 3 + 2];
    float o[32];
#pragma unroll
    for (int l = 0; l < 16; ++l) {
        float2 f = level_feat(tbl, px, py, pz, c_scal[l], (unsigned)l * TBL_T);
        o[2 * l] = f.x; o[2 * l + 1] = f.y;
        __syncthreads();
    }
    float4* dst = out + (size_t)p * 8u;
#pragma unroll
    for (int q = 0; q < 8; ++q)
        dst[q] = make_float4(o[4 * q], o[4 * q + 1], o[4 * q + 2], o[4 * q + 3]);
}

extern "C" void kernel_launch(void* const* d_in, const int* in_sizes, int n_in,
                              void* d_out, int out_size, void* d_ws, size_t ws_size,
                              hipStream_t stream) {
    const float*  x   = (const float*)d_in[0];
    const float2* tbl = (const float2*)d_in[1];   // [L*T][F=2] floats

    // ws layout: [hist 128 KB][xs4 8 MiB][15 bf16 slabs, 2 MiB each]
    const size_t off_xs4   = (size_t)NBUCK * 4u;                 // 131072
    const size_t off_slabs = off_xs4 + (size_t)NPTS * 16u;       // +8 MiB
    const size_t need      = off_slabs + (size_t)15 * NPTS * 4u; // ~38.1 MiB

    const unsigned block = 256u;
    const unsigned grid  = NPTS / block;          // 2048 blocks

    if (ws_size >= need) {
        unsigned* hist = (unsigned*)d_ws;
        float4*   xs4  = (float4*)((char*)d_ws + off_xs4);
        unsigned* slabs= (unsigned*)((char*)d_ws + off_slabs);

        zero_hist<<<NBUCK / 1024u, 1024, 0, stream>>>(hist);
        hist_k   <<<grid, block, 0, stream>>>(x, hist);
        scan32k  <<<1, 1024, 0, stream>>>(hist);
        scatter_k<<<grid, block, 0, stream>>>(x, hist, xs4);

        coarse_s <<<grid, block, 0, stream>>>(xs4, tbl, slabs);
        for (int l = 5; l < 15; ++l)
            level_s<<<grid, block, 0, stream>>>(xs4, tbl, slabs, l);
        last_s   <<<grid, block, 0, stream>>>(xs4, tbl, slabs, (float4*)d_out);
    } else {
        hashenc_mono<<<grid, block, 0, stream>>>(x, tbl, (float4*)d_out);
    }
}

// Round 11
// 237.855 us; speedup vs baseline: 1.1440x; 1.1440x over previous
//
#include <hip/hip_runtime.h>

// MultiResolutionHashEncoding, level-phased via separate launches (hard
// device-wide barrier per level => one 4 MiB slice active per XCD L2).
// Parity trick: PRIMES[0]==1 => for even ux, corners (0,iy,iz),(1,iy,iz) sit
// at table slots {2k,2k+1} -> one aligned float4 load covers both (avg 6
// gather lines/point-level instead of 8; gathers service at ~0.33
// lines/cy/CU — MSHR x latency floor, invariant to ILP/occupancy/sort).
// ws slabs stored bf16x2 (numerically free: absmax unchanged at 4.77e-7 in
// R10) -> halves last-kernel stream traffic vs f32 slabs.
// R8 lesson: only full-line output writes. R10 lesson: Morton sort nets
// negative (L2 hotspotting + sort cost >= locality gain).
//
// Scalings floor(16*growth^l) with f32 semantics of the reference
// (growth rounds DOWN in f32 => level 15 scaling is 2047, not 2048).
__device__ __constant__ float c_scal[16] = {
    16.f, 22.f, 30.f, 42.f, 58.f, 80.f, 111.f, 153.f,
    212.f, 294.f, 406.f, 561.f, 776.f, 1072.f, 1482.f, 2047.f
};

#define TBL_T 524288u   // 2^19 entries per level
#define NPTS  524288u
#define TMASK (TBL_T - 1u)

// ---------- bf16x2 pack/unpack (RNE) ----------
__device__ __forceinline__ unsigned pack_bf2(float a, float b) {
    unsigned ua = __float_as_uint(a), ub = __float_as_uint(b);
    ua = (ua + 0x7FFFu + ((ua >> 16) & 1u)) >> 16;
    ub = (ub + 0x7FFFu + ((ub >> 16) & 1u)) >> 16;
    return ua | (ub << 16);
}
__device__ __forceinline__ float2 unpack_bf2(unsigned u) {
    return make_float2(__uint_as_float(u << 16),
                       __uint_as_float(u & 0xFFFF0000u));
}

// ---------- core: one level's feature, parity-split gather ----------
__device__ __forceinline__ float2 level_feat(
        const float2* __restrict__ tbl, float px, float py, float pz,
        float s, unsigned base) {
    float sx = px * s, sy = py * s, sz = pz * s;
    float cx = floorf(sx), cy = floorf(sy), cz = floorf(sz);
    float fx = sx - cx, fy = sy - cy, fz = sz - cz;

    unsigned ux = (unsigned)cx, uy = (unsigned)cy, uz = (unsigned)cz;

    unsigned hy0 = uy * 2654435761u, hy1 = (uy + 1u) * 2654435761u;
    unsigned hz0 = uz * 805459861u,  hz1 = (uz + 1u) * 805459861u;

    float wx1 = fx, wx0 = 1.f - fx;
    float wy1 = fy, wy0 = 1.f - fy;
    float wz1 = fz, wz0 = 1.f - fz;

    float wyz[4] = { wy0 * wz0, wy0 * wz1, wy1 * wz0, wy1 * wz1 };
    unsigned hyz[4] = { hy0 ^ hz0, hy0 ^ hz1, hy1 ^ hz0, hy1 ^ hz1 };

    float o0 = 0.f, o1 = 0.f;

    if ((ux & 1u) == 0u) {
        // even ux: corners (0,iy,iz),(1,iy,iz) at slots {2k,2k+1}
        float4 f[4];
#pragma unroll
        for (int j = 0; j < 4; ++j) {
            unsigned idx0 = ((ux ^ hyz[j]) & TMASK) + base;
            f[j] = *reinterpret_cast<const float4*>(
                       reinterpret_cast<const float*>(tbl) + ((idx0 & ~1u) << 1));
        }
#pragma unroll
        for (int j = 0; j < 4; ++j) {
            unsigned idx0 = ((ux ^ hyz[j]) & TMASK) + base;
            bool hi0 = (idx0 & 1u) != 0u;
            float c0x = hi0 ? f[j].z : f[j].x;
            float c0y = hi0 ? f[j].w : f[j].y;
            float c1x = hi0 ? f[j].x : f[j].z;
            float c1y = hi0 ? f[j].y : f[j].w;
            o0 += c0x * (wx0 * wyz[j]) + c1x * (wx1 * wyz[j]);
            o1 += c0y * (wx0 * wyz[j]) + c1y * (wx1 * wyz[j]);
        }
    } else {
        // odd ux: 8 independent float2 gathers (provable minimum)
        unsigned ux1 = ux + 1u;
        float2 v0[4], v1[4];
#pragma unroll
        for (int j = 0; j < 4; ++j) {
            v0[j] = tbl[((ux  ^ hyz[j]) & TMASK) + base];
            v1[j] = tbl[((ux1 ^ hyz[j]) & TMASK) + base];
        }
#pragma unroll
        for (int j = 0; j < 4; ++j) {
            o0 += v0[j].x * (wx0 * wyz[j]) + v1[j].x * (wx1 * wyz[j]);
            o1 += v0[j].y * (wx0 * wyz[j]) + v1[j].y * (wx1 * wyz[j]);
        }
    }
    return make_float2(o0, o1);
}

// One fine level per launch (levels 5..14); writes bf16 slab.
__global__ __launch_bounds__(256) void hashenc_level(
        const float* __restrict__ x,
        const float2* __restrict__ tbl,
        unsigned* __restrict__ slabs,
        int l) {
    unsigned p = blockIdx.x * 256u + threadIdx.x;
    float px = x[p * 3 + 0], py = x[p * 3 + 1], pz = x[p * 3 + 2];
    float2 f = level_feat(tbl, px, py, pz, c_scal[l], (unsigned)l * TBL_T);
    slabs[(size_t)l * NPTS + p] = pack_bf2(f.x, f.y);
}

// Levels 0..4 fused (combined slice footprint ~2.65 MB < 4 MiB L2/XCD).
__global__ __launch_bounds__(256) void hashenc_coarse(
        const float* __restrict__ x,
        const float2* __restrict__ tbl,
        unsigned* __restrict__ slabs) {
    unsigned p = blockIdx.x * 256u + threadIdx.x;
    float px = x[p * 3 + 0], py = x[p * 3 + 1], pz = x[p * 3 + 2];
#pragma unroll
    for (int l = 0; l < 5; ++l) {
        float2 f = level_feat(tbl, px, py, pz, c_scal[l], (unsigned)l * TBL_T);
        slabs[(size_t)l * NPTS + p] = pack_bf2(f.x, f.y);
    }
}

// Level 15 + transpose fused: own gathers in registers, read 15 bf16 slabs
// coalesced, write 128 B/point contiguous final output.
__global__ __launch_bounds__(256) void hashenc_last(
        const float* __restrict__ x,
        const float2* __restrict__ tbl,
        const unsigned* __restrict__ slabs,
        float4* __restrict__ out) {
    unsigned p = blockIdx.x * 256u + threadIdx.x;
    float px = x[p * 3 + 0], py = x[p * 3 + 1], pz = x[p * 3 + 2];

    float2 f15 = level_feat(tbl, px, py, pz, c_scal[15], 15u * TBL_T);

    float2 v[15];
#pragma unroll
    for (int l = 0; l < 15; ++l) v[l] = unpack_bf2(slabs[(size_t)l * NPTS + p]);

    float4* dst = out + (size_t)p * 8u;
#pragma unroll
    for (int q = 0; q < 7; ++q)
        dst[q] = make_float4(v[2 * q].x, v[2 * q].y, v[2 * q + 1].x, v[2 * q + 1].y);
    dst[7] = make_float4(v[14].x, v[14].y, f15.x, f15.y);
}

// Fallback (ws too small): single kernel, one thread per point.
__global__ __launch_bounds__(256) void hashenc_mono(
        const float* __restrict__ x,
        const float2* __restrict__ tbl,
        float4* __restrict__ out) {
    unsigned p = blockIdx.x * 256u + threadIdx.x;
    float px = x[p * 3 + 0], py = x[p * 3 + 1], pz = x[p * 3 + 2];
    float o[32];
#pragma unroll
    for (int l = 0; l < 16; ++l) {
        float2 f = level_feat(tbl, px, py, pz, c_scal[l], (unsigned)l * TBL_T);
        o[2 * l] = f.x; o[2 * l + 1] = f.y;
        __syncthreads();
    }
    float4* dst = out + (size_t)p * 8u;
#pragma unroll
    for (int q = 0; q < 8; ++q)
        dst[q] = make_float4(o[4 * q], o[4 * q + 1], o[4 * q + 2], o[4 * q + 3]);
}

extern "C" void kernel_launch(void* const* d_in, const int* in_sizes, int n_in,
                              void* d_out, int out_size, void* d_ws, size_t ws_size,
                              hipStream_t stream) {
    const float*  x   = (const float*)d_in[0];
    const float2* tbl = (const float2*)d_in[1];   // [L*T][F=2] floats
    const size_t need = (size_t)15 * NPTS * 4u;   // 30 MiB bf16 slabs

    const unsigned block = 256u;
    const unsigned grid  = NPTS / block;          // 2048 blocks

    if (ws_size >= need) {
        unsigned* slabs = (unsigned*)d_ws;
        hashenc_coarse<<<grid, block, 0, stream>>>(x, tbl, slabs);
        for (int l = 5; l < 15; ++l)
            hashenc_level<<<grid, block, 0, stream>>>(x, tbl, slabs, l);
        hashenc_last<<<grid, block, 0, stream>>>(x, tbl, slabs, (float4*)d_out);
    } else {
        hashenc_mono<<<grid, block, 0, stream>>>(x, tbl, (float4*)d_out);
    }
}